// Round 8
// baseline (272.915 us; speedup 1.0000x reference)
//
#include <hip/hip_runtime.h>

#define N_NODES 50000
#define N_EDGES 600000
#define N_REL 8
#define NKEY_PAD 100352        // 392 * 256
#define N_TILES2 392

typedef __attribute__((ext_vector_type(8))) short bf16x8;
typedef __attribute__((ext_vector_type(4))) float f32x4;

__device__ __forceinline__ ushort f2b(float f) {
    union { float f; unsigned u; } v; v.f = f;
    unsigned r = v.u + 0x7FFFu + ((v.u >> 16) & 1u);
    return (ushort)(r >> 16);
}
__device__ __forceinline__ float b2f(ushort s) {
    union { unsigned u; float f; } v; v.u = ((unsigned)s) << 16;
    return v.f;
}

// ---------------- converts ----------------

__global__ void conv_f32_bf16(const float* __restrict__ in, ushort* __restrict__ outb) {
    int i = (blockIdx.x * 256 + threadIdx.x) * 4;
    float4 f = *(const float4*)(in + i);
    ushort4 o; o.x = f2b(f.x); o.y = f2b(f.y); o.z = f2b(f.z); o.w = f2b(f.w);
    *(ushort4*)(outb + i) = o;
}

__global__ void transpose_wts(const float* __restrict__ Wloop, const float* __restrict__ Wrel,
                              const float* __restrict__ W1, const float* __restrict__ W2,
                              ushort* __restrict__ wt) {
    int y = blockIdx.y;
    const float* src; int K, C; size_t doff;
    if (y == 0)      { src = Wloop;                       K = 128; C = 128; doff = 0; }
    else if (y <= 8) { src = Wrel + (size_t)(y - 1) * 16384; K = 128; C = 128; doff = 16384 + (size_t)(y - 1) * 16384; }
    else if (y == 9) { src = W1;                          K = 256; C = 256; doff = 147456; }
    else             { src = W2;                          K = 256; C = 128; doff = 212992; }
    int total = K * C;
    for (int idx = blockIdx.x * 256 + threadIdx.x; idx < total; idx += gridDim.x * 256) {
        int c = idx / K, k = idx - c * K;
        wt[doff + idx] = f2b(src[k * C + c]);
    }
}

// ---------------- MFMA GEMM: 128x128 block tile, 4 waves (2x2), wave tile 64x64 ----------------
// K = NPH*128 (phase p reads A-ptr Ap = p?A1:A0 with row stride AS, k-offset folded into ptr/stage).
// B panel per phase: 128 cols x 128 k staged to LDS (pad 136 shorts).
// Per wave per phase: 16 A-frag global loads (bf16), 16 ds_read_b128, 64 MFMA.
// OMODE 0: f32 out + bias, row width CTOT. OMODE 1: bf16 out slice blockIdx.y (no bias).
// OMODE 2: bf16 relu(out+bias), row width CTOT, colbase = blockIdx.y*128.
template<int NPH, int AS, int CTOT, int OMODE>
__global__ __launch_bounds__(256) void mfma_gemm(
        const ushort* __restrict__ A0, const ushort* __restrict__ A1,
        const ushort* __restrict__ Bt, const float* __restrict__ bias,
        void* __restrict__ outv) {
    __shared__ ushort bs[128 * 136];
    const int t = threadIdx.x;
    const int wave = t >> 6, lane = t & 63;
    const int lr = lane & 15, lg = lane >> 4;
    const int wr = (wave >> 1) * 64, wc = (wave & 1) * 64;
    const int row0 = blockIdx.x * 128;
    const ushort* Btb = Bt + (size_t)blockIdx.y * 128 * (NPH * 128);

    f32x4 acc[4][4];
#pragma unroll
    for (int rt = 0; rt < 4; ++rt)
#pragma unroll
        for (int nt = 0; nt < 4; ++nt) acc[rt][nt] = (f32x4){0.f, 0.f, 0.f, 0.f};

#pragma unroll
    for (int p = 0; p < NPH; ++p) {
        const ushort* Ap = p ? A1 : A0;
        // preload all A-fragments for this phase (16 x 16B, issued before barrier)
        bf16x8 af[4][4];
#pragma unroll
        for (int rt = 0; rt < 4; ++rt) {
            int ar = row0 + wr + rt * 16 + lr;
            if (ar >= N_NODES) ar = 0;
#pragma unroll
            for (int kc = 0; kc < 4; ++kc)
                af[rt][kc] = *(const bf16x8*)(Ap + (size_t)ar * AS + kc * 32 + lg * 8);
        }
        if (p) __syncthreads();   // prior phase's LDS reads complete before restage
        // stage B panel: 2048 granules of 16B; col c = idx>>4, granule gk = idx&15
#pragma unroll
        for (int it = 0; it < 8; ++it) {
            int idx = t + it * 256;
            int c = idx >> 4, gk = idx & 15;
            *(bf16x8*)(bs + c * 136 + gk * 8) =
                *(const bf16x8*)(Btb + (size_t)c * (NPH * 128) + p * 128 + gk * 8);
        }
        __syncthreads();
#pragma unroll
        for (int kc = 0; kc < 4; ++kc) {
            bf16x8 bf[4];
#pragma unroll
            for (int nt = 0; nt < 4; ++nt)
                bf[nt] = *(const bf16x8*)(bs + (wc + nt * 16 + lr) * 136 + kc * 32 + lg * 8);
#pragma unroll
            for (int rt = 0; rt < 4; ++rt)
#pragma unroll
                for (int nt = 0; nt < 4; ++nt)
                    acc[rt][nt] = __builtin_amdgcn_mfma_f32_16x16x32_bf16(af[rt][kc], bf[nt], acc[rt][nt], 0, 0, 0);
        }
    }

    const int colbase = (OMODE == 1) ? 0 : blockIdx.y * 128;
#pragma unroll
    for (int rt = 0; rt < 4; ++rt) {
#pragma unroll
        for (int nt = 0; nt < 4; ++nt) {
            const int col = colbase + wc + nt * 16 + lr;
            float bv = (OMODE == 1) ? 0.f : bias[col];
#pragma unroll
            for (int j = 0; j < 4; ++j) {
                const int r = row0 + wr + rt * 16 + lg * 4 + j;
                if (r >= N_NODES) continue;
                float vv = acc[rt][nt][j];
                if (OMODE == 0) {
                    ((float*)outv)[(size_t)r * CTOT + col] = vv + bv;
                } else if (OMODE == 1) {
                    ((ushort*)outv)[((size_t)blockIdx.y * N_NODES + r) * 128 + wc + nt * 16 + lr] = f2b(vv);
                } else {
                    ((ushort*)outv)[(size_t)r * CTOT + col] = f2b(fmaxf(vv + bv, 0.f));
                }
            }
        }
    }
}

// ---------------- CSR build, keyed by dst*2 + (etype>=4) ----------------

__global__ void zero_cnt(int* __restrict__ cnt) {
    int i = blockIdx.x * 256 + threadIdx.x;
    if (i < NKEY_PAD) cnt[i] = 0;
}

__global__ void hist_key(const int* __restrict__ dst, const int* __restrict__ et,
                         int* __restrict__ cnt) {
    int e = blockIdx.x * 256 + threadIdx.x;
    if (e < N_EDGES) atomicAdd(&cnt[dst[e] * 2 + (et[e] >> 2)], 1);
}

__global__ void scan_tiles(const int* __restrict__ cnt, int* __restrict__ tincl, int* __restrict__ bsum) {
    __shared__ int s[256];
    int i = blockIdx.x * 256 + threadIdx.x;
    int v = cnt[i];
    s[threadIdx.x] = v;
    __syncthreads();
    for (int off = 1; off < 256; off <<= 1) {
        int add = (threadIdx.x >= off) ? s[threadIdx.x - off] : 0;
        __syncthreads();
        s[threadIdx.x] += add;
        __syncthreads();
    }
    tincl[i] = s[threadIdx.x];
    if (threadIdx.x == 255) bsum[blockIdx.x] = s[255];
}

__global__ void scan_bsum(const int* __restrict__ bsum, int* __restrict__ bex) {
    __shared__ int s[512];
    int v = (threadIdx.x < N_TILES2) ? bsum[threadIdx.x] : 0;
    s[threadIdx.x] = v;
    __syncthreads();
    for (int off = 1; off < 512; off <<= 1) {
        int add = (threadIdx.x >= off) ? s[threadIdx.x - off] : 0;
        __syncthreads();
        s[threadIdx.x] += add;
        __syncthreads();
    }
    if (threadIdx.x < N_TILES2) bex[threadIdx.x] = s[threadIdx.x] - v;
}

__global__ void finalize_base(const int* __restrict__ cnt, const int* __restrict__ tincl,
                              const int* __restrict__ bex, int* __restrict__ base,
                              int* __restrict__ cursor) {
    int i = blockIdx.x * 256 + threadIdx.x;
    int b = tincl[i] - cnt[i] + bex[blockIdx.x];
    base[i] = b; cursor[i] = b;
}

__global__ void scatter_ids(const int* __restrict__ src, const int* __restrict__ dst,
                            const int* __restrict__ et, int* __restrict__ cursor,
                            unsigned* __restrict__ sorted) {
    int e = blockIdx.x * 256 + threadIdx.x;
    if (e >= N_EDGES) return;
    int pos = atomicAdd(&cursor[dst[e] * 2 + (et[e] >> 2)], 1);
    sorted[pos] = ((unsigned)src[e] << 2) | (unsigned)(et[e] & 3);
}

// ---------------- gather (atomic-free, group-split CSR, 4-way pipelined) ----------------

__device__ __forceinline__ unsigned ldrow(const ushort* __restrict__ xw, unsigned ds, int lane) {
    return *(const unsigned*)(xw + ((size_t)(ds & 3u) * N_NODES + (ds >> 2)) * 128 + lane * 2);
}

__global__ __launch_bounds__(256) void gather_mid(
        const unsigned* __restrict__ sorted, const int* __restrict__ base2,
        const int* __restrict__ cnt2, const ushort* __restrict__ xw,
        float* __restrict__ mid, int g) {
    const int w = threadIdx.x >> 6, lane = threadIdx.x & 63;
    const int n = blockIdx.x * 4 + w;
    if (n >= N_NODES) return;
    const int key = n * 2 + g;
    const int b = base2[key], c = cnt2[key];
    if (c == 0) return;

    float a0 = 0.f, a1 = 0.f, b0 = 0.f, b1 = 0.f;
    float c0 = 0.f, c1 = 0.f, d0 = 0.f, d1 = 0.f;
    const unsigned* sp = sorted + b;
    int i = 0;
    for (; i + 4 <= c; i += 4) {
        unsigned s0 = sp[i], s1 = sp[i + 1], s2 = sp[i + 2], s3 = sp[i + 3];
        unsigned v0 = ldrow(xw, s0, lane);
        unsigned v1 = ldrow(xw, s1, lane);
        unsigned v2 = ldrow(xw, s2, lane);
        unsigned v3 = ldrow(xw, s3, lane);
        a0 += b2f((ushort)(v0 & 0xffffu)); a1 += b2f((ushort)(v0 >> 16));
        b0 += b2f((ushort)(v1 & 0xffffu)); b1 += b2f((ushort)(v1 >> 16));
        c0 += b2f((ushort)(v2 & 0xffffu)); c1 += b2f((ushort)(v2 >> 16));
        d0 += b2f((ushort)(v3 & 0xffffu)); d1 += b2f((ushort)(v3 >> 16));
    }
    for (; i < c; ++i) {
        unsigned v = ldrow(xw, sp[i], lane);
        a0 += b2f((ushort)(v & 0xffffu)); a1 += b2f((ushort)(v >> 16));
    }
    float r0 = (a0 + b0) + (c0 + d0);
    float r1 = (a1 + b1) + (c1 + d1);
    float2* p = (float2*)(mid + (size_t)n * 128) + lane;
    float2 old = *p;
    old.x += r0; old.y += r1;
    *p = old;
}

// ---------------- launch ----------------

extern "C" void kernel_launch(void* const* d_in, const int* in_sizes, int n_in,
                              void* d_out, int out_size, void* d_ws, size_t ws_size,
                              hipStream_t stream) {
    const float* x     = (const float*)d_in[0];
    const int*   src   = (const int*)  d_in[1];
    const int*   dst   = (const int*)  d_in[2];
    const int*   etype = (const int*)  d_in[3];
    const float* Wrel  = (const float*)d_in[4];
    const float* Wloop = (const float*)d_in[5];
    const float* brel  = (const float*)d_in[6];
    const float* W1    = (const float*)d_in[7];
    const float* b1    = (const float*)d_in[8];
    const float* W2    = (const float*)d_in[9];
    const float* b2    = (const float*)d_in[10];
    float* out = (float*)d_out;

    // ws layout — total 81,301,248 B. ws_size = 256 MiB (fillBufferAligned WRITE_SIZE
    // = 262144 KB in the round-7 profile is the d_ws poison), so this fits.
    char* ws = (char*)d_ws;
    ushort* xw    = (ushort*)ws;                     // 51,200,000 B  4-rel bf16 slices; reused as h [50000][256] bf16
    ushort* wt    = (ushort*)(ws + 51200000);        //    491,520 B  weights bf16 transposed
    char* meta    = ws + 51691520;
    int* cnt2     = (int*)(meta);                    // 401,408 B
    int* base2    = (int*)(meta + 401408);           // 401,408 B
    int* cursor2  = (int*)(meta + 802816);           // 401,408 B
    int* tincl2   = (int*)(meta + 1204224);          // 401,408 B
    int* bsum     = (int*)(meta + 1605632);          //   2,048 B
    int* bex      = (int*)(meta + 1607680);          //   2,048 B
    unsigned* sorted = (unsigned*)(meta + 1609728);  // 2,400,000 B  (end 55,701,248)
    ushort* xbf   = (ushort*)(ws + 55701248);        // 12,800,000 B  bf16(x)
    ushort* midbf = (ushort*)(ws + 68501248);        // 12,800,000 B  bf16(mid)  (end 81,301,248)

    const ushort* wtl = wt;              // [128][128]
    const ushort* wtr = wt + 16384;      // [8][128][128]
    const ushort* w1t = wt + 147456;     // [256][256]
    const ushort* w2t = wt + 212992;     // [128][256]

    conv_f32_bf16<<<6250, 256, 0, stream>>>(x, xbf);
    transpose_wts<<<dim3(64, 11), 256, 0, stream>>>(Wloop, Wrel, W1, W2, wt);

    // CSR build, keyed by dst*2 + (etype>=4)
    zero_cnt<<<N_TILES2, 256, 0, stream>>>(cnt2);
    hist_key<<<(N_EDGES + 255) / 256, 256, 0, stream>>>(dst, etype, cnt2);
    scan_tiles<<<N_TILES2, 256, 0, stream>>>(cnt2, tincl2, bsum);
    scan_bsum<<<1, 512, 0, stream>>>(bsum, bex);
    finalize_base<<<N_TILES2, 256, 0, stream>>>(cnt2, tincl2, bex, base2, cursor2);
    scatter_ids<<<(N_EDGES + 255) / 256, 256, 0, stream>>>(src, dst, etype, cursor2, sorted);

    // mid (= d_out, f32) = x @ Wloop + brel
    mfma_gemm<1, 128, 128, 0><<<dim3(391, 1), 256, 0, stream>>>(xbf, nullptr, wtl, brel, out);

    for (int g = 0; g < 2; ++g) {
        // xw[b] = x @ Wrel[g*4+b]  (bf16), b = 0..3
        mfma_gemm<1, 128, 128, 1><<<dim3(391, 4), 256, 0, stream>>>(
            xbf, nullptr, wtr + (size_t)g * 4 * 16384, nullptr, (void*)xw);
        // mid[dst] += xw[rel_local][src]  (atomic-free, group-split CSR)
        gather_mid<<<(N_NODES + 3) / 4, 256, 0, stream>>>(sorted, base2, cnt2, xw, out, g);
    }

    // midbf = bf16(mid)
    conv_f32_bf16<<<6250, 256, 0, stream>>>(out, midbf);

    // h (bf16, in xw region) = relu(concat(x, mid) @ W1 + b1), col chunks via grid.y
    mfma_gemm<2, 128, 256, 2><<<dim3(391, 2), 256, 0, stream>>>(xbf, midbf, w1t, b1, (void*)xw);
    // out = h @ W2 + b2   (A = h with row stride 256, phase ptrs h / h+128)
    mfma_gemm<2, 256, 128, 0><<<dim3(391, 1), 256, 0, stream>>>(xw, xw + 128, w2t, b2, out);
}

// Round 9
// 261.267 us; speedup vs baseline: 1.0446x; 1.0446x over previous
//
#include <hip/hip_runtime.h>

#define N_NODES 50000
#define N_EDGES 600000
#define N_REL 8
#define NT_PAD 50176      // 196 * 256
#define N_TILES 196

typedef __attribute__((ext_vector_type(8))) short bf16x8;
typedef __attribute__((ext_vector_type(4))) float f32x4;

__device__ __forceinline__ ushort f2b(float f) {
    union { float f; unsigned u; } v; v.f = f;
    unsigned r = v.u + 0x7FFFu + ((v.u >> 16) & 1u);
    return (ushort)(r >> 16);
}
__device__ __forceinline__ float b2f(ushort s) {
    union { unsigned u; float f; } v; v.u = ((unsigned)s) << 16;
    return v.f;
}

// ---------------- converts ----------------

__global__ void conv_f32_bf16(const float* __restrict__ in, ushort* __restrict__ outb) {
    int i = (blockIdx.x * 256 + threadIdx.x) * 4;
    float4 f = *(const float4*)(in + i);
    ushort4 o; o.x = f2b(f.x); o.y = f2b(f.y); o.z = f2b(f.z); o.w = f2b(f.w);
    *(ushort4*)(outb + i) = o;
}

__global__ void transpose_wts(const float* __restrict__ Wloop, const float* __restrict__ Wrel,
                              const float* __restrict__ W1, const float* __restrict__ W2,
                              ushort* __restrict__ wt) {
    int y = blockIdx.y;
    const float* src; int K, C; size_t doff;
    if (y == 0)      { src = Wloop;                       K = 128; C = 128; doff = 0; }
    else if (y <= 8) { src = Wrel + (size_t)(y - 1) * 16384; K = 128; C = 128; doff = 16384 + (size_t)(y - 1) * 16384; }
    else if (y == 9) { src = W1;                          K = 256; C = 256; doff = 147456; }
    else             { src = W2;                          K = 256; C = 128; doff = 212992; }
    int total = K * C;
    for (int idx = blockIdx.x * 256 + threadIdx.x; idx < total; idx += gridDim.x * 256) {
        int c = idx / K, k = idx - c * K;
        wt[doff + idx] = f2b(src[k * C + c]);
    }
}

// ---------------- MFMA GEMM: 128x128 block tile, 4 waves (2x2), wave tile 64x64 ----------------
// K = NPH*128 (phase p reads A-ptr Ap = p?A1:A0 with row stride AS).
// B panel per phase: 128 cols x 128 k staged to LDS (pad 136 shorts).
// Per wave per phase: 16 A-frag global loads (bf16), 16 ds_read_b128, 64 MFMA.
// OMODE 0: f32 out + bias, row width CTOT, colbase = blockIdx.y*128.
// OMODE 2: bf16 relu(out+bias), row width CTOT, colbase = blockIdx.y*128.
// OMODE 3: fused mid+rel: y==0 -> f32 out+bias (width 128); y>=1 -> bf16 slice y-1 into outv2.
template<int NPH, int AS, int CTOT, int OMODE>
__global__ __launch_bounds__(256) void mfma_gemm(
        const ushort* __restrict__ A0, const ushort* __restrict__ A1,
        const ushort* __restrict__ Bt, const float* __restrict__ bias,
        void* __restrict__ outv, void* __restrict__ outv2) {
    __shared__ ushort bs[128 * 136];
    const int t = threadIdx.x;
    const int wave = t >> 6, lane = t & 63;
    const int lr = lane & 15, lg = lane >> 4;
    const int wr = (wave >> 1) * 64, wc = (wave & 1) * 64;
    const int row0 = blockIdx.x * 128;
    const ushort* Btb = Bt + (size_t)blockIdx.y * 128 * (NPH * 128);

    f32x4 acc[4][4];
#pragma unroll
    for (int rt = 0; rt < 4; ++rt)
#pragma unroll
        for (int nt = 0; nt < 4; ++nt) acc[rt][nt] = (f32x4){0.f, 0.f, 0.f, 0.f};

#pragma unroll
    for (int p = 0; p < NPH; ++p) {
        const ushort* Ap = p ? A1 : A0;
        // preload all A-fragments for this phase (16 x 16B, issued before barrier)
        bf16x8 af[4][4];
#pragma unroll
        for (int rt = 0; rt < 4; ++rt) {
            int ar = row0 + wr + rt * 16 + lr;
            if (ar >= N_NODES) ar = 0;
#pragma unroll
            for (int kc = 0; kc < 4; ++kc)
                af[rt][kc] = *(const bf16x8*)(Ap + (size_t)ar * AS + kc * 32 + lg * 8);
        }
        if (p) __syncthreads();   // prior phase's LDS reads complete before restage
        // stage B panel: 2048 granules of 16B; col c = idx>>4, granule gk = idx&15
#pragma unroll
        for (int it = 0; it < 8; ++it) {
            int idx = t + it * 256;
            int c = idx >> 4, gk = idx & 15;
            *(bf16x8*)(bs + c * 136 + gk * 8) =
                *(const bf16x8*)(Btb + (size_t)c * (NPH * 128) + p * 128 + gk * 8);
        }
        __syncthreads();
#pragma unroll
        for (int kc = 0; kc < 4; ++kc) {
            bf16x8 bf[4];
#pragma unroll
            for (int nt = 0; nt < 4; ++nt)
                bf[nt] = *(const bf16x8*)(bs + (wc + nt * 16 + lr) * 136 + kc * 32 + lg * 8);
#pragma unroll
            for (int rt = 0; rt < 4; ++rt)
#pragma unroll
                for (int nt = 0; nt < 4; ++nt)
                    acc[rt][nt] = __builtin_amdgcn_mfma_f32_16x16x32_bf16(af[rt][kc], bf[nt], acc[rt][nt], 0, 0, 0);
        }
    }

    const bool loopPart = (OMODE == 3) && (blockIdx.y == 0);
    const int colbase = (OMODE == 3) ? 0 : blockIdx.y * 128;
#pragma unroll
    for (int rt = 0; rt < 4; ++rt) {
#pragma unroll
        for (int nt = 0; nt < 4; ++nt) {
            const int lc = wc + nt * 16 + lr;
            const int col = colbase + lc;
            float bv = 0.f;
            if (OMODE != 3 || loopPart) bv = bias[col];
#pragma unroll
            for (int j = 0; j < 4; ++j) {
                const int r = row0 + wr + rt * 16 + lg * 4 + j;
                if (r >= N_NODES) continue;
                float vv = acc[rt][nt][j];
                if (OMODE == 0) {
                    ((float*)outv)[(size_t)r * CTOT + col] = vv + bv;
                } else if (OMODE == 2) {
                    ((ushort*)outv)[(size_t)r * CTOT + col] = f2b(fmaxf(vv + bv, 0.f));
                } else { // OMODE 3
                    if (loopPart)
                        ((float*)outv)[(size_t)r * 128 + lc] = vv + bv;
                    else
                        ((ushort*)outv2)[((size_t)(blockIdx.y - 1) * N_NODES + r) * 128 + lc] = f2b(vv);
                }
            }
        }
    }
}

// ---------------- CSR build (counting sort by dst) ----------------

__global__ void zero_cnt(int* __restrict__ cnt) {
    int i = blockIdx.x * 256 + threadIdx.x;
    if (i < NT_PAD) cnt[i] = 0;
}

__global__ void hist_dst(const int* __restrict__ dst, int* __restrict__ cnt) {
    int e = blockIdx.x * 256 + threadIdx.x;
    if (e < N_EDGES) atomicAdd(&cnt[dst[e]], 1);
}

__global__ void scan_tiles(const int* __restrict__ cnt, int* __restrict__ tincl, int* __restrict__ bsum) {
    __shared__ int s[256];
    int i = blockIdx.x * 256 + threadIdx.x;
    int v = cnt[i];
    s[threadIdx.x] = v;
    __syncthreads();
    for (int off = 1; off < 256; off <<= 1) {
        int add = (threadIdx.x >= off) ? s[threadIdx.x - off] : 0;
        __syncthreads();
        s[threadIdx.x] += add;
        __syncthreads();
    }
    tincl[i] = s[threadIdx.x];
    if (threadIdx.x == 255) bsum[blockIdx.x] = s[255];
}

__global__ void scan_bsum(const int* __restrict__ bsum, int* __restrict__ bex) {
    __shared__ int s[256];
    int v = (threadIdx.x < N_TILES) ? bsum[threadIdx.x] : 0;
    s[threadIdx.x] = v;
    __syncthreads();
    for (int off = 1; off < 256; off <<= 1) {
        int add = (threadIdx.x >= off) ? s[threadIdx.x - off] : 0;
        __syncthreads();
        s[threadIdx.x] += add;
        __syncthreads();
    }
    if (threadIdx.x < N_TILES) bex[threadIdx.x] = s[threadIdx.x] - v;
}

__global__ void finalize_base(const int* __restrict__ cnt, const int* __restrict__ tincl,
                              const int* __restrict__ bex, int* __restrict__ base,
                              int* __restrict__ cursor) {
    int i = blockIdx.x * 256 + threadIdx.x;
    int b = tincl[i] - cnt[i] + bex[blockIdx.x];
    base[i] = b; cursor[i] = b;
}

__global__ void scatter_ids(const int* __restrict__ src, const int* __restrict__ dst,
                            const int* __restrict__ et, int* __restrict__ cursor,
                            unsigned* __restrict__ sorted) {
    int e = blockIdx.x * 256 + threadIdx.x;
    if (e >= N_EDGES) return;
    int pos = atomicAdd(&cursor[dst[e]], 1);
    sorted[pos] = ((unsigned)src[e] << 3) | (unsigned)et[e];
}

// ---------------- gather (atomic-free, all 8 relations, 4-way pipelined) ----------------

__device__ __forceinline__ unsigned ldrow(const ushort* __restrict__ xw, unsigned ds, int lane) {
    return *(const unsigned*)(xw + ((size_t)(ds & 7u) * N_NODES + (ds >> 3)) * 128 + lane * 2);
}

__global__ __launch_bounds__(256) void gather_mid(
        const unsigned* __restrict__ sorted, const int* __restrict__ base,
        const int* __restrict__ cnt, const ushort* __restrict__ xw,
        float* __restrict__ mid) {
    const int w = threadIdx.x >> 6, lane = threadIdx.x & 63;
    const int n = blockIdx.x * 4 + w;
    if (n >= N_NODES) return;
    const int b = base[n], c = cnt[n];
    if (c == 0) return;

    float a0 = 0.f, a1 = 0.f, b0 = 0.f, b1 = 0.f;
    float c0 = 0.f, c1 = 0.f, d0 = 0.f, d1 = 0.f;
    const unsigned* sp = sorted + b;
    int i = 0;
    for (; i + 4 <= c; i += 4) {
        unsigned s0 = sp[i], s1 = sp[i + 1], s2 = sp[i + 2], s3 = sp[i + 3];
        unsigned v0 = ldrow(xw, s0, lane);
        unsigned v1 = ldrow(xw, s1, lane);
        unsigned v2 = ldrow(xw, s2, lane);
        unsigned v3 = ldrow(xw, s3, lane);
        a0 += b2f((ushort)(v0 & 0xffffu)); a1 += b2f((ushort)(v0 >> 16));
        b0 += b2f((ushort)(v1 & 0xffffu)); b1 += b2f((ushort)(v1 >> 16));
        c0 += b2f((ushort)(v2 & 0xffffu)); c1 += b2f((ushort)(v2 >> 16));
        d0 += b2f((ushort)(v3 & 0xffffu)); d1 += b2f((ushort)(v3 >> 16));
    }
    for (; i < c; ++i) {
        unsigned v = ldrow(xw, sp[i], lane);
        a0 += b2f((ushort)(v & 0xffffu)); a1 += b2f((ushort)(v >> 16));
    }
    float r0 = (a0 + b0) + (c0 + d0);
    float r1 = (a1 + b1) + (c1 + d1);
    float2* p = (float2*)(mid + (size_t)n * 128) + lane;
    float2 old = *p;
    old.x += r0; old.y += r1;
    *p = old;
}

// ---------------- launch ----------------

extern "C" void kernel_launch(void* const* d_in, const int* in_sizes, int n_in,
                              void* d_out, int out_size, void* d_ws, size_t ws_size,
                              hipStream_t stream) {
    const float* x     = (const float*)d_in[0];
    const int*   src   = (const int*)  d_in[1];
    const int*   dst   = (const int*)  d_in[2];
    const int*   etype = (const int*)  d_in[3];
    const float* Wrel  = (const float*)d_in[4];
    const float* Wloop = (const float*)d_in[5];
    const float* brel  = (const float*)d_in[6];
    const float* W1    = (const float*)d_in[7];
    const float* b1    = (const float*)d_in[8];
    const float* W2    = (const float*)d_in[9];
    const float* b2    = (const float*)d_in[10];
    float* out = (float*)d_out;

    // ws layout — total 131,696,384 B (ws_size = 256 MiB, confirmed by the
    // harness poison fill WRITE_SIZE = 262144 KB in the round-7/8 profiles).
    char* ws = (char*)d_ws;
    ushort* xw    = (ushort*)ws;                     // 102,400,000 B  8 rel slices bf16; reused as h [50000][256] bf16
    ushort* wt    = (ushort*)(ws + 102400000);       //     491,520 B  weights bf16 transposed
    char* meta    = ws + 102891520;
    int* cnt      = (int*)(meta);                    // 200,704 B
    int* base     = (int*)(meta + 200704);           // 200,704 B
    int* cursor   = (int*)(meta + 401408);           // 200,704 B
    int* tincl    = (int*)(meta + 602112);           // 200,704 B
    int* bsum     = (int*)(meta + 802816);           //   1,024 B
    int* bex      = (int*)(meta + 803840);           //   1,024 B
    unsigned* sorted = (unsigned*)(meta + 804864);   // 2,400,000 B  (meta end 106,096,384)
    ushort* xbf   = (ushort*)(ws + 106096384);       // 12,800,000 B  bf16(x)
    ushort* midbf = (ushort*)(ws + 118896384);       // 12,800,000 B  bf16(mid)  (end 131,696,384)

    const ushort* w1t = wt + 147456;     // [256][256]
    const ushort* w2t = wt + 212992;     // [128][256]

    conv_f32_bf16<<<6250, 256, 0, stream>>>(x, xbf);
    transpose_wts<<<dim3(64, 11), 256, 0, stream>>>(Wloop, Wrel, W1, W2, wt);

    // CSR build (counting sort of edges by dst)
    zero_cnt<<<N_TILES, 256, 0, stream>>>(cnt);
    hist_dst<<<(N_EDGES + 255) / 256, 256, 0, stream>>>(dst, cnt);
    scan_tiles<<<N_TILES, 256, 0, stream>>>(cnt, tincl, bsum);
    scan_bsum<<<1, 256, 0, stream>>>(bsum, bex);
    finalize_base<<<N_TILES, 256, 0, stream>>>(cnt, tincl, bex, base, cursor);
    scatter_ids<<<(N_EDGES + 255) / 256, 256, 0, stream>>>(src, dst, etype, cursor, sorted);

    // fused: y=0 -> mid(=out,f32) = x@Wloop + brel; y=1..8 -> xw[y-1] = x@Wrel[y-1] (bf16)
    // (wt layout: Wloop at 0, rels contiguous after -> Btb = wt + y*16384 is exact)
    mfma_gemm<1, 128, 128, 3><<<dim3(391, 9), 256, 0, stream>>>(
        xbf, nullptr, wt, brel, out, (void*)xw);

    // mid[dst] += xw[etype][src]  (atomic-free, single pass over all 8 relations)
    gather_mid<<<(N_NODES + 3) / 4, 256, 0, stream>>>(sorted, base, cnt, xw, out);

    // midbf = bf16(mid)
    conv_f32_bf16<<<6250, 256, 0, stream>>>(out, midbf);

    // h (bf16, in xw region) = relu(concat(x, mid) @ W1 + b1), col chunks via grid.y
    mfma_gemm<2, 128, 256, 2><<<dim3(391, 2), 256, 0, stream>>>(
        xbf, midbf, w1t, b1, (void*)xw, nullptr);
    // out = h @ W2 + b2   (A = h with row stride 256, phase ptrs h / h+128)
    mfma_gemm<2, 256, 128, 0><<<dim3(391, 1), 256, 0, stream>>>(
        xw, xw + 128, w2t, b2, out, nullptr);
}

// Round 10
// 236.008 us; speedup vs baseline: 1.1564x; 1.1070x over previous
//
#include <hip/hip_runtime.h>

#define N_NODES 50000
#define N_EDGES 600000
#define N_REL 8
#define NT_PAD 50176      // 196 * 256
#define N_TILES 196

typedef __attribute__((ext_vector_type(8))) short bf16x8;
typedef __attribute__((ext_vector_type(4))) float f32x4;

__device__ __forceinline__ ushort f2b(float f) {
    union { float f; unsigned u; } v; v.f = f;
    unsigned r = v.u + 0x7FFFu + ((v.u >> 16) & 1u);
    return (ushort)(r >> 16);
}
__device__ __forceinline__ float b2f(ushort s) {
    union { unsigned u; float f; } v; v.u = ((unsigned)s) << 16;
    return v.f;
}

// ---------------- converts / weight prep ----------------

__global__ void conv_f32_bf16(const float* __restrict__ in, ushort* __restrict__ outb) {
    int i = (blockIdx.x * 256 + threadIdx.x) * 4;
    float4 f = *(const float4*)(in + i);
    ushort4 o; o.x = f2b(f.x); o.y = f2b(f.y); o.z = f2b(f.z); o.w = f2b(f.w);
    *(ushort4*)(outb + i) = o;
}

// wst [128 cols][1152 k] = stack(Wrel[0..7], Wloop)^T ; w1t [256][256]; w2t [128][256]
__global__ void transpose_wts3(const float* __restrict__ Wloop, const float* __restrict__ Wrel,
                               const float* __restrict__ W1, const float* __restrict__ W2,
                               ushort* __restrict__ wt) {
    int y = blockIdx.y;
    if (y == 0) {
        for (int idx = blockIdx.x * 256 + threadIdx.x; idx < 128 * 1152; idx += gridDim.x * 256) {
            int c = idx / 1152, kg = idx - c * 1152;
            float v = (kg < 1024) ? Wrel[(size_t)((kg >> 7) * 128 + (kg & 127)) * 128 + c]
                                  : Wloop[(size_t)(kg - 1024) * 128 + c];
            wt[idx] = f2b(v);
        }
    } else if (y == 1) {
        for (int idx = blockIdx.x * 256 + threadIdx.x; idx < 256 * 256; idx += gridDim.x * 256) {
            int c = idx >> 8, k = idx & 255;
            wt[147456 + idx] = f2b(W1[k * 256 + c]);
        }
    } else {
        for (int idx = blockIdx.x * 256 + threadIdx.x; idx < 128 * 256; idx += gridDim.x * 256) {
            int c = idx >> 8, k = idx & 255;
            wt[212992 + idx] = f2b(W2[k * 128 + c]);
        }
    }
}

// ---------------- MFMA GEMM: 128x128 block tile, 4 waves (2x2), wave tile 64x64 ----------------
// KMODE 0 (NPH=9): phase p<8 reads A0 + p*128 (stride 1024 = agg), p==8 reads A1 (stride 128 = xbf).
// KMODE 1 (NPH<=2): phase p reads (p?A1:A0), stride AS.
// B panel per phase: 128 cols x 128 k staged to LDS (pad 136 shorts); Bt row stride = NPH*128.
// OMODE 0: f32 out+bias, width CTOT, colbase=y*128.  OMODE 2: bf16 relu(out+bias), width CTOT.
// OMODE 4: bf16 out+bias, width 128.
template<int NPH, int KMODE, int AS, int CTOT, int OMODE>
__global__ __launch_bounds__(256) void mfma_gemm(
        const ushort* __restrict__ A0, const ushort* __restrict__ A1,
        const ushort* __restrict__ Bt, const float* __restrict__ bias,
        void* __restrict__ outv) {
    __shared__ ushort bs[128 * 136];
    const int t = threadIdx.x;
    const int wave = t >> 6, lane = t & 63;
    const int lr = lane & 15, lg = lane >> 4;
    const int wr = (wave >> 1) * 64, wc = (wave & 1) * 64;
    const int row0 = blockIdx.x * 128;
    const ushort* Btb = Bt + (size_t)blockIdx.y * 128 * (NPH * 128);

    f32x4 acc[4][4];
#pragma unroll
    for (int rt = 0; rt < 4; ++rt)
#pragma unroll
        for (int nt = 0; nt < 4; ++nt) acc[rt][nt] = (f32x4){0.f, 0.f, 0.f, 0.f};

#pragma unroll
    for (int p = 0; p < NPH; ++p) {
        const ushort* Ap; int as_;
        if (KMODE == 0) {
            if (p < 8) { Ap = A0 + p * 128; as_ = 1024; }
            else       { Ap = A1;           as_ = 128; }
        } else {
            Ap = p ? A1 : A0; as_ = AS;
        }
        // preload A fragments for this phase
        bf16x8 af[4][4];
#pragma unroll
        for (int rt = 0; rt < 4; ++rt) {
            int ar = row0 + wr + rt * 16 + lr;
            if (ar >= N_NODES) ar = 0;
#pragma unroll
            for (int kc = 0; kc < 4; ++kc)
                af[rt][kc] = *(const bf16x8*)(Ap + (size_t)ar * as_ + kc * 32 + lg * 8);
        }
        if (p) __syncthreads();   // prior phase's LDS reads complete before restage
        // stage B panel: 2048 granules of 16B; col c = idx>>4, granule gk = idx&15
#pragma unroll
        for (int it = 0; it < 8; ++it) {
            int idx = t + it * 256;
            int c = idx >> 4, gk = idx & 15;
            *(bf16x8*)(bs + c * 136 + gk * 8) =
                *(const bf16x8*)(Btb + (size_t)c * (NPH * 128) + p * 128 + gk * 8);
        }
        __syncthreads();
#pragma unroll
        for (int kc = 0; kc < 4; ++kc) {
            bf16x8 bf[4];
#pragma unroll
            for (int nt = 0; nt < 4; ++nt)
                bf[nt] = *(const bf16x8*)(bs + (wc + nt * 16 + lr) * 136 + kc * 32 + lg * 8);
#pragma unroll
            for (int rt = 0; rt < 4; ++rt)
#pragma unroll
                for (int nt = 0; nt < 4; ++nt)
                    acc[rt][nt] = __builtin_amdgcn_mfma_f32_16x16x32_bf16(af[rt][kc], bf[nt], acc[rt][nt], 0, 0, 0);
        }
    }

    const int colbase = blockIdx.y * 128;
#pragma unroll
    for (int rt = 0; rt < 4; ++rt) {
#pragma unroll
        for (int nt = 0; nt < 4; ++nt) {
            const int col = colbase + wc + nt * 16 + lr;
            const float bv = bias[col];
#pragma unroll
            for (int j = 0; j < 4; ++j) {
                const int r = row0 + wr + rt * 16 + lg * 4 + j;
                if (r >= N_NODES) continue;
                float vv = acc[rt][nt][j] + bv;
                if (OMODE == 0) {
                    ((float*)outv)[(size_t)r * CTOT + col] = vv;
                } else if (OMODE == 2) {
                    ((ushort*)outv)[(size_t)r * CTOT + col] = f2b(fmaxf(vv, 0.f));
                } else { // OMODE 4
                    ((ushort*)outv)[(size_t)r * 128 + col] = f2b(vv);
                }
            }
        }
    }
}

// ---------------- CSR build (counting sort by dst) ----------------

__global__ void zero_cnt(int* __restrict__ cnt) {
    int i = blockIdx.x * 256 + threadIdx.x;
    if (i < NT_PAD) cnt[i] = 0;
}

__global__ void hist_dst(const int* __restrict__ dst, int* __restrict__ cnt) {
    int e = blockIdx.x * 256 + threadIdx.x;
    if (e < N_EDGES) atomicAdd(&cnt[dst[e]], 1);
}

__global__ void scan_tiles(const int* __restrict__ cnt, int* __restrict__ tincl, int* __restrict__ bsum) {
    __shared__ int s[256];
    int i = blockIdx.x * 256 + threadIdx.x;
    int v = cnt[i];
    s[threadIdx.x] = v;
    __syncthreads();
    for (int off = 1; off < 256; off <<= 1) {
        int add = (threadIdx.x >= off) ? s[threadIdx.x - off] : 0;
        __syncthreads();
        s[threadIdx.x] += add;
        __syncthreads();
    }
    tincl[i] = s[threadIdx.x];
    if (threadIdx.x == 255) bsum[blockIdx.x] = s[255];
}

__global__ void scan_bsum(const int* __restrict__ bsum, int* __restrict__ bex) {
    __shared__ int s[256];
    int v = (threadIdx.x < N_TILES) ? bsum[threadIdx.x] : 0;
    s[threadIdx.x] = v;
    __syncthreads();
    for (int off = 1; off < 256; off <<= 1) {
        int add = (threadIdx.x >= off) ? s[threadIdx.x - off] : 0;
        __syncthreads();
        s[threadIdx.x] += add;
        __syncthreads();
    }
    if (threadIdx.x < N_TILES) bex[threadIdx.x] = s[threadIdx.x] - v;
}

__global__ void finalize_base(const int* __restrict__ cnt, const int* __restrict__ tincl,
                              const int* __restrict__ bex, int* __restrict__ base,
                              int* __restrict__ cursor) {
    int i = blockIdx.x * 256 + threadIdx.x;
    int b = tincl[i] - cnt[i] + bex[blockIdx.x];
    base[i] = b; cursor[i] = b;
}

__global__ void scatter_ids(const int* __restrict__ src, const int* __restrict__ dst,
                            const int* __restrict__ et, int* __restrict__ cursor,
                            unsigned* __restrict__ sorted) {
    int e = blockIdx.x * 256 + threadIdx.x;
    if (e >= N_EDGES) return;
    int pos = atomicAdd(&cursor[dst[e]], 1);
    sorted[pos] = ((unsigned)src[e] << 3) | (unsigned)et[e];
}

// ---------------- gather_agg: agg[n][r*128+c] = sum_{e: dst=n, etype=r} x[src_e][c] ----------------
// one wave per dst node; lane owns 2 adjacent columns; 8 statically-indexed f32 acc pairs.

__global__ __launch_bounds__(256) void gather_agg(
        const unsigned* __restrict__ sorted, const int* __restrict__ base,
        const int* __restrict__ cnt, const ushort* __restrict__ xbf,
        ushort* __restrict__ agg) {
    const int w = threadIdx.x >> 6, lane = threadIdx.x & 63;
    const int n = blockIdx.x * 4 + w;
    const int b = base[n], c = cnt[n];

    float a0[8], a1[8];
#pragma unroll
    for (int r = 0; r < 8; ++r) { a0[r] = 0.f; a1[r] = 0.f; }

    const unsigned* sp = sorted + b;
    int i = 0;
    for (; i + 4 <= c; i += 4) {
        unsigned d0 = sp[i], d1 = sp[i + 1], d2 = sp[i + 2], d3 = sp[i + 3];
        unsigned v0 = *(const unsigned*)(xbf + (size_t)(d0 >> 3) * 128 + lane * 2);
        unsigned v1 = *(const unsigned*)(xbf + (size_t)(d1 >> 3) * 128 + lane * 2);
        unsigned v2 = *(const unsigned*)(xbf + (size_t)(d2 >> 3) * 128 + lane * 2);
        unsigned v3 = *(const unsigned*)(xbf + (size_t)(d3 >> 3) * 128 + lane * 2);
#pragma unroll
        for (int r = 0; r < 8; ++r) {
            if ((d0 & 7u) == (unsigned)r) { a0[r] += b2f((ushort)(v0 & 0xffffu)); a1[r] += b2f((ushort)(v0 >> 16)); }
            if ((d1 & 7u) == (unsigned)r) { a0[r] += b2f((ushort)(v1 & 0xffffu)); a1[r] += b2f((ushort)(v1 >> 16)); }
            if ((d2 & 7u) == (unsigned)r) { a0[r] += b2f((ushort)(v2 & 0xffffu)); a1[r] += b2f((ushort)(v2 >> 16)); }
            if ((d3 & 7u) == (unsigned)r) { a0[r] += b2f((ushort)(v3 & 0xffffu)); a1[r] += b2f((ushort)(v3 >> 16)); }
        }
    }
    for (; i < c; ++i) {
        unsigned d = sp[i];
        unsigned v = *(const unsigned*)(xbf + (size_t)(d >> 3) * 128 + lane * 2);
#pragma unroll
        for (int r = 0; r < 8; ++r) {
            if ((d & 7u) == (unsigned)r) { a0[r] += b2f((ushort)(v & 0xffffu)); a1[r] += b2f((ushort)(v >> 16)); }
        }
    }
    // write 8 packed bf16 pairs (zeros included — required by segment_sum semantics)
#pragma unroll
    for (int r = 0; r < 8; ++r) {
        unsigned pk = (unsigned)f2b(a0[r]) | ((unsigned)f2b(a1[r]) << 16);
        *(unsigned*)(agg + (size_t)n * 1024 + r * 128 + lane * 2) = pk;
    }
}

// ---------------- launch ----------------

extern "C" void kernel_launch(void* const* d_in, const int* in_sizes, int n_in,
                              void* d_out, int out_size, void* d_ws, size_t ws_size,
                              hipStream_t stream) {
    const float* x     = (const float*)d_in[0];
    const int*   src   = (const int*)  d_in[1];
    const int*   dst   = (const int*)  d_in[2];
    const int*   etype = (const int*)  d_in[3];
    const float* Wrel  = (const float*)d_in[4];
    const float* Wloop = (const float*)d_in[5];
    const float* brel  = (const float*)d_in[6];
    const float* W1    = (const float*)d_in[7];
    const float* b1    = (const float*)d_in[8];
    const float* W2    = (const float*)d_in[9];
    const float* b2    = (const float*)d_in[10];
    float* out = (float*)d_out;

    // ws layout — total 131,696,384 B (ws_size = 256 MiB, confirmed round 7/8).
    char* ws = (char*)d_ws;
    ushort* agg   = (ushort*)ws;                     // 102,400,000 B  [N][1024] bf16; reused as h [N][256] bf16
    ushort* wt    = (ushort*)(ws + 102400000);       //     491,520 B  wst/w1t/w2t
    char* meta    = ws + 102891520;
    int* cnt      = (int*)(meta);                    // 200,704 B
    int* base     = (int*)(meta + 200704);           // 200,704 B
    int* cursor   = (int*)(meta + 401408);           // 200,704 B
    int* tincl    = (int*)(meta + 602112);           // 200,704 B
    int* bsum     = (int*)(meta + 802816);           //   1,024 B
    int* bex      = (int*)(meta + 803840);           //   1,024 B
    unsigned* sorted = (unsigned*)(meta + 804864);   // 2,400,000 B  (meta end 106,096,384)
    ushort* xbf   = (ushort*)(ws + 106096384);       // 12,800,000 B  bf16(x)
    ushort* midbf = (ushort*)(ws + 118896384);       // 12,800,000 B  bf16(mid)  (end 131,696,384)

    const ushort* wst = wt;              // [128][1152]  stack(Wrel, Wloop)^T
    const ushort* w1t = wt + 147456;     // [256][256]
    const ushort* w2t = wt + 212992;     // [128][256]
    ushort* h = agg;                     // [N][256] bf16 (agg dead after mega-GEMM)

    conv_f32_bf16<<<6250, 256, 0, stream>>>(x, xbf);
    transpose_wts3<<<dim3(64, 3), 256, 0, stream>>>(Wloop, Wrel, W1, W2, wt);

    // CSR build (counting sort of edges by dst)
    zero_cnt<<<N_TILES, 256, 0, stream>>>(cnt);
    hist_dst<<<(N_EDGES + 255) / 256, 256, 0, stream>>>(dst, cnt);
    scan_tiles<<<N_TILES, 256, 0, stream>>>(cnt, tincl, bsum);
    scan_bsum<<<1, 256, 0, stream>>>(bsum, bex);
    finalize_base<<<N_TILES, 256, 0, stream>>>(cnt, tincl, bex, base, cursor);
    scatter_ids<<<(N_EDGES + 255) / 256, 256, 0, stream>>>(src, dst, etype, cursor, sorted);

    // agg[n][r] = sum of x[src] over edges (dst=n, etype=r)
    gather_agg<<<N_NODES / 4, 256, 0, stream>>>(sorted, base, cnt, xbf, agg);

    // midbf = bf16( concat(agg_0..7, x) @ stack(Wrel, Wloop) + brel )   (K = 1152)
    mfma_gemm<9, 0, 0, 128, 4><<<dim3(391, 1), 256, 0, stream>>>(agg, xbf, wst, brel, (void*)midbf);

    // h = relu(concat(x, mid) @ W1 + b1)  bf16, col chunks via grid.y
    mfma_gemm<2, 1, 128, 256, 2><<<dim3(391, 2), 256, 0, stream>>>(xbf, midbf, w1t, b1, (void*)h);

    // out = h @ W2 + b2  (f32)
    mfma_gemm<2, 1, 256, 128, 0><<<dim3(391, 1), 256, 0, stream>>>(h, h + 128, w2t, b2, out);
}

// Round 11
// 222.367 us; speedup vs baseline: 1.2273x; 1.0613x over previous
//
#include <hip/hip_runtime.h>

#define N_NODES 50000
#define N_EDGES 600000
#define N_REL 8
#define NT_PAD 50176      // 196 * 256
#define N_TILES 196

typedef __attribute__((ext_vector_type(8))) short bf16x8;
typedef __attribute__((ext_vector_type(4))) float f32x4;

__device__ __forceinline__ ushort f2b(float f) {
    union { float f; unsigned u; } v; v.f = f;
    unsigned r = v.u + 0x7FFFu + ((v.u >> 16) & 1u);
    return (ushort)(r >> 16);
}
__device__ __forceinline__ float b2f(ushort s) {
    union { unsigned u; float f; } v; v.u = ((unsigned)s) << 16;
    return v.f;
}

// ---------------- converts / weight prep ----------------

__global__ void conv_f32_bf16(const float* __restrict__ in, ushort* __restrict__ outb) {
    int i = (blockIdx.x * 256 + threadIdx.x) * 4;
    float4 f = *(const float4*)(in + i);
    ushort4 o; o.x = f2b(f.x); o.y = f2b(f.y); o.z = f2b(f.z); o.w = f2b(f.w);
    *(ushort4*)(outb + i) = o;
}

// wst [128 cols][1152 k] = stack(Wrel[0..7], Wloop)^T ; w1t [256][256]; w2t [128][256]
__global__ void transpose_wts3(const float* __restrict__ Wloop, const float* __restrict__ Wrel,
                               const float* __restrict__ W1, const float* __restrict__ W2,
                               ushort* __restrict__ wt) {
    int y = blockIdx.y;
    if (y == 0) {
        for (int idx = blockIdx.x * 256 + threadIdx.x; idx < 128 * 1152; idx += gridDim.x * 256) {
            int c = idx / 1152, kg = idx - c * 1152;
            float v = (kg < 1024) ? Wrel[(size_t)((kg >> 7) * 128 + (kg & 127)) * 128 + c]
                                  : Wloop[(size_t)(kg - 1024) * 128 + c];
            wt[idx] = f2b(v);
        }
    } else if (y == 1) {
        for (int idx = blockIdx.x * 256 + threadIdx.x; idx < 256 * 256; idx += gridDim.x * 256) {
            int c = idx >> 8, k = idx & 255;
            wt[147456 + idx] = f2b(W1[k * 256 + c]);
        }
    } else {
        for (int idx = blockIdx.x * 256 + threadIdx.x; idx < 128 * 256; idx += gridDim.x * 256) {
            int c = idx >> 8, k = idx & 255;
            wt[212992 + idx] = f2b(W2[k * 128 + c]);
        }
    }
}

// ---------------- MFMA GEMM: 128x128 block tile, 4 waves (2x2), wave tile 64x64 ----------------
// Double-buffered B panel in LDS + one-phase-ahead A prefetch.
// KMODE 0 (NPH=9): phase p<8 reads A0 + p*128 (stride 1024 = agg), p==8 reads A1 (stride 128).
// KMODE 1 (NPH<=2): phase p reads (p?A1:A0), stride AS.
// OMODE 0: f32 out+bias, width CTOT, colbase=y*128.  OMODE 2: bf16 relu(out+bias), width CTOT.
// OMODE 4: bf16 out+bias, width 128.
template<int NPH, int KMODE, int AS, int CTOT, int OMODE>
__global__ __launch_bounds__(256, 2) void mfma_gemm(
        const ushort* __restrict__ A0, const ushort* __restrict__ A1,
        const ushort* __restrict__ Bt, const float* __restrict__ bias,
        void* __restrict__ outv) {
    __shared__ ushort bs[2][128 * 136];
    const int t = threadIdx.x;
    const int wave = t >> 6, lane = t & 63;
    const int lr = lane & 15, lg = lane >> 4;
    const int wr = (wave >> 1) * 64, wc = (wave & 1) * 64;
    const int row0 = blockIdx.x * 128;
    const ushort* Btb = Bt + (size_t)blockIdx.y * 128 * (NPH * 128);
    // staging coords: per thread gk = t&15 (x8 shorts), cols sc0 + it*16
    const int sgk = (t & 15) * 8;
    const int sc0 = t >> 4;

#define STAGE_LOAD(p)                                                              \
    _Pragma("unroll")                                                              \
    for (int it = 0; it < 8; ++it)                                                 \
        sreg[it] = *(const bf16x8*)(Btb + (size_t)(sc0 + it * 16) * (NPH * 128) +  \
                                    (p) * 128 + sgk);

#define STAGE_WRITE(b)                                                             \
    _Pragma("unroll")                                                              \
    for (int it = 0; it < 8; ++it)                                                 \
        *(bf16x8*)(&bs[b][(sc0 + it * 16) * 136 + sgk]) = sreg[it];

#define LOAD_AF(p, dstf)                                                           \
    {                                                                              \
        const ushort* Ap; int as_;                                                 \
        if (KMODE == 0) {                                                          \
            if ((p) < 8) { Ap = A0 + (p) * 128; as_ = 1024; }                      \
            else         { Ap = A1;             as_ = 128;  }                      \
        } else { Ap = (p) ? A1 : A0; as_ = AS; }                                   \
        _Pragma("unroll")                                                          \
        for (int rt = 0; rt < 4; ++rt) {                                           \
            int ar = row0 + wr + rt * 16 + lr;                                     \
            if (ar >= N_NODES) ar = 0;                                             \
            _Pragma("unroll")                                                      \
            for (int kc = 0; kc < 4; ++kc)                                         \
                dstf[rt][kc] = *(const bf16x8*)(Ap + (size_t)ar * as_ + kc * 32 + lg * 8); \
        }                                                                          \
    }

    f32x4 acc[4][4];
#pragma unroll
    for (int rt = 0; rt < 4; ++rt)
#pragma unroll
        for (int nt = 0; nt < 4; ++nt) acc[rt][nt] = (f32x4){0.f, 0.f, 0.f, 0.f};

    bf16x8 af[4][4], afn[4][4], sreg[8];

    STAGE_LOAD(0);
    LOAD_AF(0, af);
    STAGE_WRITE(0);
    __syncthreads();

#pragma unroll
    for (int p = 0; p < NPH; ++p) {
        if (p + 1 < NPH) {
            STAGE_LOAD(p + 1);       // global loads in flight under compute
            LOAD_AF(p + 1, afn);
        }
        const ushort* bcur = bs[p & 1];
#pragma unroll
        for (int kc = 0; kc < 4; ++kc) {
            bf16x8 bf[4];
#pragma unroll
            for (int nt = 0; nt < 4; ++nt)
                bf[nt] = *(const bf16x8*)(bcur + (wc + nt * 16 + lr) * 136 + kc * 32 + lg * 8);
#pragma unroll
            for (int rt = 0; rt < 4; ++rt)
#pragma unroll
                for (int nt = 0; nt < 4; ++nt)
                    acc[rt][nt] = __builtin_amdgcn_mfma_f32_16x16x32_bf16(af[rt][kc], bf[nt], acc[rt][nt], 0, 0, 0);
        }
        if (p + 1 < NPH) {
            STAGE_WRITE((p + 1) & 1);   // write-late: after compute
        }
        __syncthreads();
        if (p + 1 < NPH) {
#pragma unroll
            for (int rt = 0; rt < 4; ++rt)
#pragma unroll
                for (int kc = 0; kc < 4; ++kc) af[rt][kc] = afn[rt][kc];
        }
    }

    const int colbase = blockIdx.y * 128;
#pragma unroll
    for (int rt = 0; rt < 4; ++rt) {
#pragma unroll
        for (int nt = 0; nt < 4; ++nt) {
            const int col = colbase + wc + nt * 16 + lr;
            const float bv = bias[col];
#pragma unroll
            for (int j = 0; j < 4; ++j) {
                const int r = row0 + wr + rt * 16 + lg * 4 + j;
                if (r >= N_NODES) continue;
                float vv = acc[rt][nt][j] + bv;
                if (OMODE == 0) {
                    ((float*)outv)[(size_t)r * CTOT + col] = vv;
                } else if (OMODE == 2) {
                    ((ushort*)outv)[(size_t)r * CTOT + col] = f2b(fmaxf(vv, 0.f));
                } else { // OMODE 4
                    ((ushort*)outv)[(size_t)r * 128 + col] = f2b(vv);
                }
            }
        }
    }
#undef STAGE_LOAD
#undef STAGE_WRITE
#undef LOAD_AF
}

// ---------------- CSR build (counting sort by dst) ----------------

__global__ void zero_cnt(int* __restrict__ cnt) {
    int i = blockIdx.x * 256 + threadIdx.x;
    if (i < NT_PAD) cnt[i] = 0;
}

__global__ void hist_dst(const int* __restrict__ dst, int* __restrict__ cnt) {
    int e = blockIdx.x * 256 + threadIdx.x;
    if (e < N_EDGES) atomicAdd(&cnt[dst[e]], 1);
}

__global__ void scan_tiles(const int* __restrict__ cnt, int* __restrict__ tincl, int* __restrict__ bsum) {
    __shared__ int s[256];
    int i = blockIdx.x * 256 + threadIdx.x;
    int v = cnt[i];
    s[threadIdx.x] = v;
    __syncthreads();
    for (int off = 1; off < 256; off <<= 1) {
        int add = (threadIdx.x >= off) ? s[threadIdx.x - off] : 0;
        __syncthreads();
        s[threadIdx.x] += add;
        __syncthreads();
    }
    tincl[i] = s[threadIdx.x];
    if (threadIdx.x == 255) bsum[blockIdx.x] = s[255];
}

__global__ void scan_bsum(const int* __restrict__ bsum, int* __restrict__ bex) {
    __shared__ int s[256];
    int v = (threadIdx.x < N_TILES) ? bsum[threadIdx.x] : 0;
    s[threadIdx.x] = v;
    __syncthreads();
    for (int off = 1; off < 256; off <<= 1) {
        int add = (threadIdx.x >= off) ? s[threadIdx.x - off] : 0;
        __syncthreads();
        s[threadIdx.x] += add;
        __syncthreads();
    }
    if (threadIdx.x < N_TILES) bex[threadIdx.x] = s[threadIdx.x] - v;
}

__global__ void finalize_base(const int* __restrict__ cnt, const int* __restrict__ tincl,
                              const int* __restrict__ bex, int* __restrict__ base,
                              int* __restrict__ cursor) {
    int i = blockIdx.x * 256 + threadIdx.x;
    int b = tincl[i] - cnt[i] + bex[blockIdx.x];
    base[i] = b; cursor[i] = b;
}

__global__ void scatter_ids(const int* __restrict__ src, const int* __restrict__ dst,
                            const int* __restrict__ et, int* __restrict__ cursor,
                            unsigned* __restrict__ sorted) {
    int e = blockIdx.x * 256 + threadIdx.x;
    if (e >= N_EDGES) return;
    int pos = atomicAdd(&cursor[dst[e]], 1);
    sorted[pos] = ((unsigned)src[e] << 3) | (unsigned)et[e];
}

// ---------------- gather_agg: agg[n][r*128+c] = sum_{e: dst=n, etype=r} x[src_e][c] ----------------

__global__ __launch_bounds__(256) void gather_agg(
        const unsigned* __restrict__ sorted, const int* __restrict__ base,
        const int* __restrict__ cnt, const ushort* __restrict__ xbf,
        ushort* __restrict__ agg) {
    const int w = threadIdx.x >> 6, lane = threadIdx.x & 63;
    const int n = blockIdx.x * 4 + w;
    const int b = base[n], c = cnt[n];

    float a0[8], a1[8];
#pragma unroll
    for (int r = 0; r < 8; ++r) { a0[r] = 0.f; a1[r] = 0.f; }

    const unsigned* sp = sorted + b;
    int i = 0;
    for (; i + 4 <= c; i += 4) {
        unsigned d0 = sp[i], d1 = sp[i + 1], d2 = sp[i + 2], d3 = sp[i + 3];
        unsigned v0 = *(const unsigned*)(xbf + (size_t)(d0 >> 3) * 128 + lane * 2);
        unsigned v1 = *(const unsigned*)(xbf + (size_t)(d1 >> 3) * 128 + lane * 2);
        unsigned v2 = *(const unsigned*)(xbf + (size_t)(d2 >> 3) * 128 + lane * 2);
        unsigned v3 = *(const unsigned*)(xbf + (size_t)(d3 >> 3) * 128 + lane * 2);
#pragma unroll
        for (int r = 0; r < 8; ++r) {
            if ((d0 & 7u) == (unsigned)r) { a0[r] += b2f((ushort)(v0 & 0xffffu)); a1[r] += b2f((ushort)(v0 >> 16)); }
            if ((d1 & 7u) == (unsigned)r) { a0[r] += b2f((ushort)(v1 & 0xffffu)); a1[r] += b2f((ushort)(v1 >> 16)); }
            if ((d2 & 7u) == (unsigned)r) { a0[r] += b2f((ushort)(v2 & 0xffffu)); a1[r] += b2f((ushort)(v2 >> 16)); }
            if ((d3 & 7u) == (unsigned)r) { a0[r] += b2f((ushort)(v3 & 0xffffu)); a1[r] += b2f((ushort)(v3 >> 16)); }
        }
    }
    for (; i < c; ++i) {
        unsigned d = sp[i];
        unsigned v = *(const unsigned*)(xbf + (size_t)(d >> 3) * 128 + lane * 2);
#pragma unroll
        for (int r = 0; r < 8; ++r) {
            if ((d & 7u) == (unsigned)r) { a0[r] += b2f((ushort)(v & 0xffffu)); a1[r] += b2f((ushort)(v >> 16)); }
        }
    }
#pragma unroll
    for (int r = 0; r < 8; ++r) {
        unsigned pk = (unsigned)f2b(a0[r]) | ((unsigned)f2b(a1[r]) << 16);
        *(unsigned*)(agg + (size_t)n * 1024 + r * 128 + lane * 2) = pk;
    }
}

// ---------------- launch ----------------

extern "C" void kernel_launch(void* const* d_in, const int* in_sizes, int n_in,
                              void* d_out, int out_size, void* d_ws, size_t ws_size,
                              hipStream_t stream) {
    const float* x     = (const float*)d_in[0];
    const int*   src   = (const int*)  d_in[1];
    const int*   dst   = (const int*)  d_in[2];
    const int*   etype = (const int*)  d_in[3];
    const float* Wrel  = (const float*)d_in[4];
    const float* Wloop = (const float*)d_in[5];
    const float* brel  = (const float*)d_in[6];
    const float* W1    = (const float*)d_in[7];
    const float* b1    = (const float*)d_in[8];
    const float* W2    = (const float*)d_in[9];
    const float* b2    = (const float*)d_in[10];
    float* out = (float*)d_out;

    // ws layout — total 131,696,384 B (ws_size = 256 MiB, confirmed round 7/8).
    char* ws = (char*)d_ws;
    ushort* agg   = (ushort*)ws;                     // 102,400,000 B  [N][1024] bf16; reused as h [N][256] bf16
    ushort* wt    = (ushort*)(ws + 102400000);       //     491,520 B  wst/w1t/w2t
    char* meta    = ws + 102891520;
    int* cnt      = (int*)(meta);                    // 200,704 B
    int* base     = (int*)(meta + 200704);           // 200,704 B
    int* cursor   = (int*)(meta + 401408);           // 200,704 B
    int* tincl    = (int*)(meta + 602112);           // 200,704 B
    int* bsum     = (int*)(meta + 802816);           //   1,024 B
    int* bex      = (int*)(meta + 803840);           //   1,024 B
    unsigned* sorted = (unsigned*)(meta + 804864);   // 2,400,000 B  (meta end 106,096,384)
    ushort* xbf   = (ushort*)(ws + 106096384);       // 12,800,000 B  bf16(x)
    ushort* midbf = (ushort*)(ws + 118896384);       // 12,800,000 B  bf16(mid)  (end 131,696,384)

    const ushort* wst = wt;              // [128][1152]  stack(Wrel, Wloop)^T
    const ushort* w1t = wt + 147456;     // [256][256]
    const ushort* w2t = wt + 212992;     // [128][256]
    ushort* h = agg;                     // [N][256] bf16 (agg dead after mega-GEMM)

    conv_f32_bf16<<<6250, 256, 0, stream>>>(x, xbf);
    transpose_wts3<<<dim3(64, 3), 256, 0, stream>>>(Wloop, Wrel, W1, W2, wt);

    // CSR build (counting sort of edges by dst)
    zero_cnt<<<N_TILES, 256, 0, stream>>>(cnt);
    hist_dst<<<(N_EDGES + 255) / 256, 256, 0, stream>>>(dst, cnt);
    scan_tiles<<<N_TILES, 256, 0, stream>>>(cnt, tincl, bsum);
    scan_bsum<<<1, 256, 0, stream>>>(bsum, bex);
    finalize_base<<<N_TILES, 256, 0, stream>>>(cnt, tincl, bex, base, cursor);
    scatter_ids<<<(N_EDGES + 255) / 256, 256, 0, stream>>>(src, dst, etype, cursor, sorted);

    // agg[n][r] = sum of x[src] over edges (dst=n, etype=r)
    gather_agg<<<N_NODES / 4, 256, 0, stream>>>(sorted, base, cnt, xbf, agg);

    // midbf = bf16( concat(agg_0..7, x) @ stack(Wrel, Wloop) + brel )   (K = 1152)
    mfma_gemm<9, 0, 0, 128, 4><<<dim3(391, 1), 256, 0, stream>>>(agg, xbf, wst, brel, (void*)midbf);

    // h = relu(concat(x, mid) @ W1 + b1)  bf16, col chunks via grid.y
    mfma_gemm<2, 1, 128, 256, 2><<<dim3(391, 2), 256, 0, stream>>>(xbf, midbf, w1t, b1, (void*)h);

    // out = h @ W2 + b2  (f32)
    mfma_gemm<2, 1, 256, 128, 0><<<dim3(391, 1), 256, 0, stream>>>(h, h + 128, w2t, b2, out);
}